// Round 18
// baseline (46.960 us; speedup 1.0000x reference)
//
#include <hip/hip_runtime.h>
#include <math.h>

#define BB 4
#define ND 256
#define NE 512
#define CC 256

#define K2E 2.8853900817779268f   // 2 * log2(e): exp2(K2E*x) = e^{2x}
#define LOG2E 1.4426950408889634f
#define LN2 0.6931471805599453f

typedef unsigned int u32;
typedef unsigned short u16;
typedef __attribute__((ext_vector_type(8))) short bf16x8;   // 8 bf16 (4 VGPR)
typedef __attribute__((ext_vector_type(4))) float f32x4;
typedef __attribute__((ext_vector_type(4))) u32   u32x4;

__device__ __forceinline__ float bflo(u32 u) { return __builtin_bit_cast(float, u << 16); }
__device__ __forceinline__ float bfhi(u32 u) { return __builtin_bit_cast(float, u & 0xffff0000u); }

// pack 2 f32 -> 1 u32 of 2 bf16 (lo in [15:0], hi in [31:16])
__device__ __forceinline__ u32 cvt_pk(float lo, float hi) {
    u32 r;
    asm("v_cvt_pk_bf16_f32 %0, %1, %2" : "=v"(r) : "v"(lo), "v"(hi));
    return r;
}

__device__ __forceinline__ bf16x8 mk_frag(float4 f0, float4 f1) {
    u32x4 q;
    q.x = cvt_pk(f0.x, f0.y);
    q.y = cvt_pk(f0.z, f0.w);
    q.z = cvt_pk(f1.x, f1.y);
    q.w = cvt_pk(f1.z, f1.w);
    return __builtin_bit_cast(bf16x8, q);
}

// ---------------------------------------------------------------------------
// MFMA projection — IDENTICAL to R17 (measurement round: launched twice;
// T18 - T17 = proj duration exactly).
// ---------------------------------------------------------------------------
__global__ __launch_bounds__(256) void proj_kernel(
    const float* __restrict__ xdec, const float* __restrict__ xenc,
    const float* __restrict__ w1,   const float* __restrict__ w2,
    uint4* __restrict__ Et4, float* __restrict__ Dexp)
{
    __shared__ float Ct[64][17];   // C staging for enc pack-transpose

    const int row0 = blockIdx.x * 64;     // M base (0..3071)
    const int col0 = blockIdx.y * 16;     // N base (0..240)
    const bool is_enc = (row0 < BB * NE);

    const float* X = is_enc ? xenc : xdec;
    const float* W = is_enc ? w1   : w2;
    const int xrow0 = is_enc ? row0 : (row0 - BB * NE);

    const int tid = threadIdx.x;
    const int wv  = tid >> 6;        // wave 0..3
    const int l   = tid & 63;
    const int lm  = l & 15;          // fragment row (A) / col (B)
    const int kg  = l >> 4;          // k-group 0..3

    const float* Arow = X + (size_t)(xrow0 + wv * 16 + lm) * CC + kg * 8;
    const float* Brow = W + (size_t)(col0 + lm) * CC + kg * 8;

    f32x4 acc = {0.f, 0.f, 0.f, 0.f};
#pragma unroll
    for (int ks = 0; ks < 8; ++ks) {
        const float* ap = Arow + ks * 32;
        const float* bp = Brow + ks * 32;
        bf16x8 af = mk_frag(*(const float4*)ap, *(const float4*)(ap + 4));
        bf16x8 bf = mk_frag(*(const float4*)bp, *(const float4*)(bp + 4));
        acc = __builtin_amdgcn_mfma_f32_16x16x32_bf16(af, bf, acc, 0, 0, 0);
    }

    float ex[4];
#pragma unroll
    for (int i = 0; i < 4; ++i)
        ex[i] = __builtin_amdgcn_exp2f(
            K2E * fminf(fmaxf(acc[i], -9.f), 9.f));

    if (is_enc) {
#pragma unroll
        for (int i = 0; i < 4; ++i)
            Ct[wv * 16 + kg * 4 + i][lm] = ex[i];
        __syncthreads();
        if (tid < 128) {
            const int e   = tid & 63;
            const int cqL = tid >> 6;        // 0..1
            const int b   = row0 >> 9;
            const int e0  = row0 & 511;
            const float* cr = &Ct[e][cqL * 8];
            u32x4 q;
            q.x = cvt_pk(cr[0], cr[1]);
            q.y = cvt_pk(cr[2], cr[3]);
            q.z = cvt_pk(cr[4], cr[5]);
            q.w = cvt_pk(cr[6], cr[7]);
            Et4[((size_t)b * 32 + (col0 >> 3) + cqL) * 512 + e0 + e] =
                __builtin_bit_cast(uint4, q);
        }
    } else {
        const int n = xrow0 + wv * 16 + kg * 4;
#pragma unroll
        for (int i = 0; i < 4; ++i)
            Dexp[(size_t)(n + i) * CC + col0 + lm] = ex[i];
    }
}

// ---------------------------------------------------------------------------
// Fused tanh-dot + log_softmax — R12/R17 VERBATIM (anchor).
// ---------------------------------------------------------------------------
__global__ __launch_bounds__(512) void attn_kernel(
    const uint4* __restrict__ Et4, const float* __restrict__ Dexp,
    const float* __restrict__ v, float* __restrict__ out)
{
    __shared__ float prod[2][NE];

    const int blk = blockIdx.x;       // 0..511
    const int b   = blk >> 7;
    const int n0  = (blk & 127) * 2;
    const int tid = threadIdx.x;      // == e

    const float* __restrict__ D0 = Dexp + (size_t)(b * ND + n0) * CC;
    const float* __restrict__ D1 = D0 + CC;
    const uint4* Ec = Et4 + (size_t)b * 32 * 512 + tid;

    float a0 = 0.f, a1 = 0.f;

#define PAIR(ACC, E0, E1, V0, V1, Dx0, Dx1) do {                             \
        const float _d0 = fmaf((E0), (Dx0), 1.0f);                           \
        const float _d1 = fmaf((E1), (Dx1), 1.0f);                           \
        const float _num = fmaf((V1), _d0, (V0) * _d1);                      \
        ACC = fmaf(_num, __builtin_amdgcn_rcpf(_d0 * _d1), ACC);             \
    } while (0)

#define PROC(E4, CQ) do {                                                    \
        const int c8 = (CQ) * 8;                                             \
        const float4 vA  = *(const float4*)&v [c8];                          \
        const float4 vB  = *(const float4*)&v [c8 + 4];                      \
        const float4 dA0 = *(const float4*)&D0[c8];                          \
        const float4 dB0 = *(const float4*)&D0[c8 + 4];                      \
        const float4 dA1 = *(const float4*)&D1[c8];                          \
        const float4 dB1 = *(const float4*)&D1[c8 + 4];                      \
        PAIR(a0, bflo(E4.x), bfhi(E4.x), vA.x, vA.y, dA0.x, dA0.y);          \
        PAIR(a1, bflo(E4.x), bfhi(E4.x), vA.x, vA.y, dA1.x, dA1.y);          \
        PAIR(a0, bflo(E4.y), bfhi(E4.y), vA.z, vA.w, dA0.z, dA0.w);          \
        PAIR(a1, bflo(E4.y), bfhi(E4.y), vA.z, vA.w, dA1.z, dA1.w);          \
        PAIR(a0, bflo(E4.z), bfhi(E4.z), vB.x, vB.y, dB0.x, dB0.y);          \
        PAIR(a1, bflo(E4.z), bfhi(E4.z), vB.x, vB.y, dB1.x, dB1.y);          \
        PAIR(a0, bflo(E4.w), bfhi(E4.w), vB.z, vB.w, dB0.z, dB0.w);          \
        PAIR(a1, bflo(E4.w), bfhi(E4.w), vB.z, vB.w, dB1.z, dB1.w);          \
    } while (0)

    uint4 e4a = Ec[0], e4b;
    for (int cq = 0; cq < 32; cq += 2) {
        e4b = Ec[(size_t)(cq + 1) * 512];
        PROC(e4a, cq);
        if (cq + 2 < 32) e4a = Ec[(size_t)(cq + 2) * 512];
        PROC(e4b, cq + 1);
    }
#undef PROC
#undef PAIR

    prod[0][tid] = -2.0f * a0;
    prod[1][tid] = -2.0f * a1;
    __syncthreads();

    const int w    = tid >> 6;
    const int lane = tid & 63;
    if (w < 2) {
        float p[8];
#pragma unroll
        for (int i = 0; i < 8; ++i) p[i] = prod[w][lane + 64 * i];
        float m = p[0];
#pragma unroll
        for (int i = 1; i < 8; ++i) m = fmaxf(m, p[i]);
#pragma unroll
        for (int off = 1; off < 64; off <<= 1) m = fmaxf(m, __shfl_xor(m, off));
        float s = 0.f;
#pragma unroll
        for (int i = 0; i < 8; ++i) s += __builtin_amdgcn_exp2f((p[i] - m) * LOG2E);
#pragma unroll
        for (int off = 1; off < 64; off <<= 1) s += __shfl_xor(s, off);
        const float lse = m + __builtin_amdgcn_logf(s) * LN2;

        float* o = out + (size_t)(b * ND + n0 + w) * NE;
#pragma unroll
        for (int i = 0; i < 8; ++i) o[lane + 64 * i] = p[i] - lse;
    }
}

// ---------------------------------------------------------------------------
extern "C" void kernel_launch(void* const* d_in, const int* in_sizes, int n_in,
                              void* d_out, int out_size, void* d_ws, size_t ws_size,
                              hipStream_t stream) {
    const float* xdec = (const float*)d_in[0];   // (4,256,256)
    const float* xenc = (const float*)d_in[1];   // (4,512,256)
    const float* w1   = (const float*)d_in[2];   // (256,256)
    const float* w2   = (const float*)d_in[3];   // (256,256)
    const float* v    = (const float*)d_in[4];   // (1,256)
    float* out = (float*)d_out;                  // (4,256,512)

    char* ws = (char*)d_ws;
    uint4* Et4  = (uint4*)ws;                    // [4][32][512] uint4 = 1 MB
    float* Dexp = (float*)(ws + (1u << 20));     // [1024][256] f32 = 1 MB

    dim3 gproj(48, 16);
    // MEASUREMENT ROUND: proj launched TWICE (idempotent, byte-identical to
    // R17). T18 - T17 = proj_mfma duration exactly. Remove next round.
    proj_kernel<<<gproj, 256, 0, stream>>>(xdec, xenc, w1, w2, Et4, Dexp);
    proj_kernel<<<gproj, 256, 0, stream>>>(xdec, xenc, w1, w2, Et4, Dexp);
    attn_kernel<<<(BB * ND) / 2, 512, 0, stream>>>(Et4, Dexp, v, out);
}

// Round 19
// 36.409 us; speedup vs baseline: 1.2898x; 1.2898x over previous
//
#include <hip/hip_runtime.h>
#include <math.h>

#define BB 4
#define ND 256
#define NE 512
#define CC 256

#define K2E 2.8853900817779268f   // 2 * log2(e): exp2(K2E*x) = e^{2x}
#define LOG2E 1.4426950408889634f
#define LN2 0.6931471805599453f

typedef unsigned int u32;
typedef unsigned short u16;
typedef __attribute__((ext_vector_type(8))) short bf16x8;   // 8 bf16 (4 VGPR)
typedef __attribute__((ext_vector_type(4))) float f32x4;
typedef __attribute__((ext_vector_type(4))) u32   u32x4;
typedef __attribute__((ext_vector_type(2))) float v2f;      // -> v_pk_*_f32

__device__ __forceinline__ float bflo(u32 u) { return __builtin_bit_cast(float, u << 16); }
__device__ __forceinline__ float bfhi(u32 u) { return __builtin_bit_cast(float, u & 0xffff0000u); }

__device__ __forceinline__ v2f fma2(v2f a, v2f b, v2f c) {
    return __builtin_elementwise_fma(a, b, c);
}

// pack 2 f32 -> 1 u32 of 2 bf16 (lo in [15:0], hi in [31:16])
__device__ __forceinline__ u32 cvt_pk(float lo, float hi) {
    u32 r;
    asm("v_cvt_pk_bf16_f32 %0, %1, %2" : "=v"(r) : "v"(lo), "v"(hi));
    return r;
}

__device__ __forceinline__ bf16x8 mk_frag(float4 f0, float4 f1) {
    u32x4 q;
    q.x = cvt_pk(f0.x, f0.y);
    q.y = cvt_pk(f0.z, f0.w);
    q.z = cvt_pk(f1.x, f1.y);
    q.w = cvt_pk(f1.z, f1.w);
    return __builtin_bit_cast(bf16x8, q);
}

// ---------------------------------------------------------------------------
// MFMA projection — R17 VERBATIM (11.9us measured R18; not the target this
// round).
// ---------------------------------------------------------------------------
__global__ __launch_bounds__(256) void proj_kernel(
    const float* __restrict__ xdec, const float* __restrict__ xenc,
    const float* __restrict__ w1,   const float* __restrict__ w2,
    uint4* __restrict__ Et4, float* __restrict__ Dexp)
{
    __shared__ float Ct[64][17];   // C staging for enc pack-transpose

    const int row0 = blockIdx.x * 64;     // M base (0..3071)
    const int col0 = blockIdx.y * 16;     // N base (0..240)
    const bool is_enc = (row0 < BB * NE);

    const float* X = is_enc ? xenc : xdec;
    const float* W = is_enc ? w1   : w2;
    const int xrow0 = is_enc ? row0 : (row0 - BB * NE);

    const int tid = threadIdx.x;
    const int wv  = tid >> 6;        // wave 0..3
    const int l   = tid & 63;
    const int lm  = l & 15;          // fragment row (A) / col (B)
    const int kg  = l >> 4;          // k-group 0..3

    const float* Arow = X + (size_t)(xrow0 + wv * 16 + lm) * CC + kg * 8;
    const float* Brow = W + (size_t)(col0 + lm) * CC + kg * 8;

    f32x4 acc = {0.f, 0.f, 0.f, 0.f};
#pragma unroll
    for (int ks = 0; ks < 8; ++ks) {
        const float* ap = Arow + ks * 32;
        const float* bp = Brow + ks * 32;
        bf16x8 af = mk_frag(*(const float4*)ap, *(const float4*)(ap + 4));
        bf16x8 bf = mk_frag(*(const float4*)bp, *(const float4*)(bp + 4));
        acc = __builtin_amdgcn_mfma_f32_16x16x32_bf16(af, bf, acc, 0, 0, 0);
    }

    float ex[4];
#pragma unroll
    for (int i = 0; i < 4; ++i)
        ex[i] = __builtin_amdgcn_exp2f(
            K2E * fminf(fmaxf(acc[i], -9.f), 9.f));

    if (is_enc) {
#pragma unroll
        for (int i = 0; i < 4; ++i)
            Ct[wv * 16 + kg * 4 + i][lm] = ex[i];
        __syncthreads();
        if (tid < 128) {
            const int e   = tid & 63;
            const int cqL = tid >> 6;        // 0..1
            const int b   = row0 >> 9;
            const int e0  = row0 & 511;
            const float* cr = &Ct[e][cqL * 8];
            u32x4 q;
            q.x = cvt_pk(cr[0], cr[1]);
            q.y = cvt_pk(cr[2], cr[3]);
            q.z = cvt_pk(cr[4], cr[5]);
            q.w = cvt_pk(cr[6], cr[7]);
            Et4[((size_t)b * 32 + (col0 >> 3) + cqL) * 512 + e0 + e] =
                __builtin_bit_cast(uint4, q);
        }
    } else {
        const int n = xrow0 + wv * 16 + kg * 4;
#pragma unroll
        for (int i = 0; i < 4; ++i)
            Dexp[(size_t)(n + i) * CC + col0 + lm] = ex[i];
    }
}

// ---------------------------------------------------------------------------
// Fused tanh-dot + log_softmax — PACKED-FP32 inner loop.
//   p'[n,e] = -2 * sum_c v_c / (1 + E*D)    (sum(v) shift cancels)
// Per c-pair per row: 1 v_pk_fma (d), 2 v_rcp, 1 v_pk_fma (acc) — even/odd-c
// lanes accumulate separately (no horizontal ops until the end). This halves
// the VALU issue slots vs the scalar form (R13: VALU-issue-bound, 65% busy).
// 512 thr (tid = e), 2 decoder rows/block, 512 blocks — structure unchanged.
// ---------------------------------------------------------------------------
__global__ __launch_bounds__(512) void attn_kernel(
    const uint4* __restrict__ Et4, const float* __restrict__ Dexp,
    const float* __restrict__ v, float* __restrict__ out)
{
    __shared__ float prod[2][NE];

    const int blk = blockIdx.x;       // 0..511
    const int b   = blk >> 7;
    const int n0  = (blk & 127) * 2;
    const int tid = threadIdx.x;      // == e

    const float* __restrict__ D0 = Dexp + (size_t)(b * ND + n0) * CC;
    const float* __restrict__ D1 = D0 + CC;
    const uint4* Ec = Et4 + (size_t)b * 32 * 512 + tid;

    const v2f one2 = {1.0f, 1.0f};
    v2f a0v = {0.f, 0.f}, a1v = {0.f, 0.f};

#define STEP(W, VP, D0P, D1P) do {                                           \
        const v2f E2 = {bflo(W), bfhi(W)};                                   \
        const v2f d0 = fma2(E2, (D0P), one2);                                \
        const v2f d1 = fma2(E2, (D1P), one2);                                \
        const v2f r0 = {__builtin_amdgcn_rcpf(d0.x),                         \
                        __builtin_amdgcn_rcpf(d0.y)};                        \
        const v2f r1 = {__builtin_amdgcn_rcpf(d1.x),                         \
                        __builtin_amdgcn_rcpf(d1.y)};                        \
        a0v = fma2((VP), r0, a0v);                                           \
        a1v = fma2((VP), r1, a1v);                                           \
    } while (0)

#define PROC(E4, CQ) do {                                                    \
        const int c8 = (CQ) * 8;                                             \
        const float4 vA  = *(const float4*)&v [c8];                          \
        const float4 vB  = *(const float4*)&v [c8 + 4];                      \
        const float4 dA0 = *(const float4*)&D0[c8];                          \
        const float4 dB0 = *(const float4*)&D0[c8 + 4];                      \
        const float4 dA1 = *(const float4*)&D1[c8];                          \
        const float4 dB1 = *(const float4*)&D1[c8 + 4];                      \
        STEP(E4.x, ((v2f){vA.x, vA.y}), ((v2f){dA0.x, dA0.y}),               \
                   ((v2f){dA1.x, dA1.y}));                                   \
        STEP(E4.y, ((v2f){vA.z, vA.w}), ((v2f){dA0.z, dA0.w}),               \
                   ((v2f){dA1.z, dA1.w}));                                   \
        STEP(E4.z, ((v2f){vB.x, vB.y}), ((v2f){dB0.x, dB0.y}),               \
                   ((v2f){dB1.x, dB1.y}));                                   \
        STEP(E4.w, ((v2f){vB.z, vB.w}), ((v2f){dB0.z, dB0.w}),               \
                   ((v2f){dB1.z, dB1.w}));                                   \
    } while (0)

    uint4 e4a = Ec[0], e4b;
    for (int cq = 0; cq < 32; cq += 2) {
        e4b = Ec[(size_t)(cq + 1) * 512];
        PROC(e4a, cq);
        if (cq + 2 < 32) e4a = Ec[(size_t)(cq + 2) * 512];
        PROC(e4b, cq + 1);
    }
#undef PROC
#undef STEP

    prod[0][tid] = -2.0f * (a0v.x + a0v.y);
    prod[1][tid] = -2.0f * (a1v.x + a1v.y);
    __syncthreads();

    // log_softmax: wave w (w<2) handles decoder row n0+w
    const int w    = tid >> 6;
    const int lane = tid & 63;
    if (w < 2) {
        float p[8];
#pragma unroll
        for (int i = 0; i < 8; ++i) p[i] = prod[w][lane + 64 * i];
        float m = p[0];
#pragma unroll
        for (int i = 1; i < 8; ++i) m = fmaxf(m, p[i]);
#pragma unroll
        for (int off = 1; off < 64; off <<= 1) m = fmaxf(m, __shfl_xor(m, off));
        float s = 0.f;
#pragma unroll
        for (int i = 0; i < 8; ++i) s += __builtin_amdgcn_exp2f((p[i] - m) * LOG2E);
#pragma unroll
        for (int off = 1; off < 64; off <<= 1) s += __shfl_xor(s, off);
        const float lse = m + __builtin_amdgcn_logf(s) * LN2;

        float* o = out + (size_t)(b * ND + n0 + w) * NE;
#pragma unroll
        for (int i = 0; i < 8; ++i) o[lane + 64 * i] = p[i] - lse;
    }
}

// ---------------------------------------------------------------------------
extern "C" void kernel_launch(void* const* d_in, const int* in_sizes, int n_in,
                              void* d_out, int out_size, void* d_ws, size_t ws_size,
                              hipStream_t stream) {
    const float* xdec = (const float*)d_in[0];   // (4,256,256)
    const float* xenc = (const float*)d_in[1];   // (4,512,256)
    const float* w1   = (const float*)d_in[2];   // (256,256)
    const float* w2   = (const float*)d_in[3];   // (256,256)
    const float* v    = (const float*)d_in[4];   // (1,256)
    float* out = (float*)d_out;                  // (4,256,512)

    char* ws = (char*)d_ws;
    uint4* Et4  = (uint4*)ws;                    // [4][32][512] uint4 = 1 MB
    float* Dexp = (float*)(ws + (1u << 20));     // [1024][256] f32 = 1 MB

    dim3 gproj(48, 16);
    proj_kernel<<<gproj, 256, 0, stream>>>(xdec, xenc, w1, w2, Et4, Dexp);
    attn_kernel<<<(BB * ND) / 2, 512, 0, stream>>>(Et4, Dexp, v, out);
}